// Round 5
// baseline (131.990 us; speedup 1.0000x reference)
//
#include <hip/hip_runtime.h>
#include <math.h>

typedef _Float16 f16_t;
typedef __attribute__((ext_vector_type(8))) _Float16 f16x8;
typedef __attribute__((ext_vector_type(4))) float f32x4;

#define NTOK 131072
#define MT   256      // tokens per block
#define TPB  256      // 4 waves; each wave owns 64 tokens (M=64 tile)
#define RP16 72       // relay pitch (f16)
#define OP32 68       // out-stage pitch (f32)
#define SLABB 9216    // per-wave slab: relay 64*72*2

// ws layout (f16 elems)
#define OFF_KEY 0
#define OFF_VAL 4096
#define OFF_T   8192
#define OFF_D1  40960
#define OFF_D2  45056
#define OFF_D3  47104
#define WTOT    49152

__device__ __forceinline__ f32x4 mfma1(f16x8 a, f16x8 b, f32x4 c) {
    return __builtin_amdgcn_mfma_f32_16x16x32_f16(a, b, c, 0, 0, 0);
}

// ---- DPP 16-lane butterfly reductions (VALU, no LDS round-trips) ----------
// Reduction group = lanes [quad*16, quad*16+15] = exactly one DPP row.
// Steps: quad_perm xor1 (0xB1), quad_perm xor2 (0x4E), row_half_mirror
// (0x141, i^7 -> other quad of half), row_mirror (0x140, i^15 -> other half).
#define DPPF(x, C) __int_as_float(__builtin_amdgcn_update_dpp( \
    0, __float_as_int(x), (C), 0xF, 0xF, true))

__device__ __forceinline__ void red16_sum4(f32x4& x) {
#pragma unroll
    for (int e = 0; e < 4; ++e) {
        float v = x[e];
        v += DPPF(v, 0xB1);
        v += DPPF(v, 0x4E);
        v += DPPF(v, 0x141);
        v += DPPF(v, 0x140);
        x[e] = v;
    }
}
__device__ __forceinline__ void red16_max4(f32x4& x) {
#pragma unroll
    for (int e = 0; e < 4; ++e) {
        float v = x[e];
        v = fmaxf(v, DPPF(v, 0xB1));
        v = fmaxf(v, DPPF(v, 0x4E));
        v = fmaxf(v, DPPF(v, 0x141));
        v = fmaxf(v, DPPF(v, 0x140));
        x[e] = v;
    }
}

struct B2 { f16x8 b0, b1; };

// LDS B-fragment read, XOR-swizzled (128B-row panels). Proven conflict-clean in R3.
__device__ __forceinline__ B2 loadB_lds(const f16_t* __restrict__ b, int c, int l15, int quad) {
    const char* base = (const char*)b;
    int o0 = (16 * c + l15) * 128 + quad * 16;
    int sw = (l15 & 7) << 4;
    B2 r;
    r.b0 = *(const f16x8*)(base + (o0 ^ sw));
    r.b1 = *(const f16x8*)(base + ((o0 + 64) ^ sw));
    return r;
}

#define GEMML(buf, c, a00, a01, a10, a11, acc0, acc1) do {        \
    B2 Bf = loadB_lds((buf), (c), l15, quad);                      \
    acc0 = mfma1(a01, Bf.b1, mfma1(a00, Bf.b0, acc0));             \
    acc1 = mfma1(a11, Bf.b1, mfma1(a10, Bf.b0, acc1));             \
} while (0)

// T-stage column step: ONE B-fragment pair feeds FOUR row-tiles (B-reuse=4).
#define TCOL(tb, c, QA0, QA1, QA2, QA3, Q0, Q1, Q2, Q3) do {       \
    B2 Bf = loadB_lds((tb), (c), l15, quad);                        \
    f32x4 z = {};                                                   \
    f32x4 tt0 = mfma1(ah01, Bf.b1, mfma1(ah00, Bf.b0, z));          \
    Q0 += QA0 * tt0;                                                \
    f32x4 tt1 = mfma1(ah11, Bf.b1, mfma1(ah10, Bf.b0, z));          \
    Q1 += QA1 * tt1;                                                \
    f32x4 tt2 = mfma1(ah21, Bf.b1, mfma1(ah20, Bf.b0, z));          \
    Q2 += QA2 * tt2;                                                \
    f32x4 tt3 = mfma1(ah31, Bf.b1, mfma1(ah30, Bf.b0, z));          \
    Q3 += QA3 * tt3;                                                \
} while (0)

// async global->LDS DMA, 16B/lane; LDS dest linear (base + lane*16)
__device__ __forceinline__ void gl_lds16(const void* g, void* l) {
    __builtin_amdgcn_global_load_lds(
        (const __attribute__((address_space(1))) unsigned int*)g,
        (__attribute__((address_space(3))) unsigned int*)l, 16, 0, 0);
}

// Stage an 8KB 128B-row panel; swizzle applied as inverse perm on the GLOBAL src
// (both-sides-or-neither rule): LDS[row][col ^ ((row&7)<<4)] = G[row][col].
__device__ __forceinline__ void stage8k(const f16_t* __restrict__ gsrc, f16_t* lbuf, int tid) {
#pragma unroll
    for (int i = 0; i < 2; ++i) {
        int o = (i * 256 + tid) * 16;
        int g = o ^ (((o >> 7) & 7) << 4);
        gl_lds16((const char*)gsrc + g, (char*)lbuf + (o & ~1023));
    }
}
__device__ __forceinline__ void stage4k_r128(const f16_t* __restrict__ gsrc, f16_t* lbuf, int tid) {
    int o = tid * 16;
    int g = o ^ (((o >> 7) & 7) << 4);
    gl_lds16((const char*)gsrc + g, (char*)lbuf + (o & ~1023));
}
// 64B-row panel (d3): swizzle XORs bits 4-5 with row>>1
__device__ __forceinline__ void stage4k_r64(const f16_t* __restrict__ gsrc, f16_t* lbuf, int tid) {
    int o = tid * 16;
    int g = o ^ (((o >> 7) & 3) << 4);
    gl_lds16((const char*)gsrc + g, (char*)lbuf + (o & ~1023));
}

// counted vmcnt + raw barrier (NEVER __syncthreads: it drains vmcnt(0))
#define VMW2() asm volatile("s_waitcnt vmcnt(2)" ::: "memory")
#define VMW0() asm volatile("s_waitcnt vmcnt(0)" ::: "memory")
#define BAR()  do { __builtin_amdgcn_s_barrier(); asm volatile("" ::: "memory"); } while (0)

// ---------------- prep: transpose all weights into ws as fp16 --------------
__global__ __launch_bounds__(256)
void prep_w(const float* __restrict__ keyW, const float* __restrict__ valW,
            const float* __restrict__ TW,   const float* __restrict__ TB,
            const float* __restrict__ d1W,  const float* __restrict__ d2W,
            const float* __restrict__ d3W,  f16_t* __restrict__ wsf)
{
    int idx = blockIdx.x * 256 + threadIdx.x;
    if (idx >= WTOT) return;
    float src;
    if (idx < OFF_VAL) {
        int r = idx - OFF_KEY, n = r >> 6, j = r & 63;
        src = keyW[j * 64 + n];
    } else if (idx < OFF_T) {
        int r = idx - OFF_VAL, n = r >> 6, j = r & 63;
        src = valW[j * 64 + n];
    } else if (idx < OFF_D1) {
        int r = idx - OFF_T, p = r >> 12, q = r & 4095;
        src = (p < 7) ? TW[p * 4096 + q] : TB[q];
    } else if (idx < OFF_D2) {
        int r = idx - OFF_D1, n = r >> 6, j = r & 63;
        src = d1W[j * 64 + n];
    } else if (idx < OFF_D3) {
        int r = idx - OFF_D2, n = r >> 6, j = r & 63;
        src = d2W[j * 32 + n];
    } else {
        int r = idx - OFF_D3, n = r >> 5, j = r & 31;
        src = d3W[j * 64 + n];
    }
    wsf[idx] = (f16_t)src;
}

// per-row-tile front: k|v GEMM (LDS-staged) + softmax + att + normalize + relay.
__device__ __forceinline__ void front_rt(
    f16_t* __restrict__ Rf,
    const f16_t* __restrict__ keyb, const f16_t* __restrict__ valb,
    int l15, int quad, int rtb,
    f16x8 a0, f16x8 a1,
    f32x4 q0, f32x4 q1, f32x4 q2, f32x4 q3,
    f32x4 kbv, f32x4 vbv, float sc)
{
    f32x4 k0 = {}, k1 = {}, k2 = {}, k3 = {}, v0 = {}, v1 = {}, v2 = {}, v3 = {};
    { B2 B = loadB_lds(keyb, 0, l15, quad); k0 = mfma1(a1, B.b1, mfma1(a0, B.b0, k0)); }
    { B2 B = loadB_lds(keyb, 1, l15, quad); k1 = mfma1(a1, B.b1, mfma1(a0, B.b0, k1)); }
    { B2 B = loadB_lds(keyb, 2, l15, quad); k2 = mfma1(a1, B.b1, mfma1(a0, B.b0, k2)); }
    { B2 B = loadB_lds(keyb, 3, l15, quad); k3 = mfma1(a1, B.b1, mfma1(a0, B.b0, k3)); }
    { B2 B = loadB_lds(valb, 0, l15, quad); v0 = mfma1(a1, B.b1, mfma1(a0, B.b0, v0)); }
    { B2 B = loadB_lds(valb, 1, l15, quad); v1 = mfma1(a1, B.b1, mfma1(a0, B.b0, v1)); }
    { B2 B = loadB_lds(valb, 2, l15, quad); v2 = mfma1(a1, B.b1, mfma1(a0, B.b0, v2)); }
    { B2 B = loadB_lds(valb, 3, l15, quad); v3 = mfma1(a1, B.b1, mfma1(a0, B.b0, v3)); }

    f32x4 sv0 = (v0 + vbv[0]) * sc;
    f32x4 sv1 = (v1 + vbv[1]) * sc;
    f32x4 sv2 = (v2 + vbv[2]) * sc;
    f32x4 sv3 = (v3 + vbv[3]) * sc;

    f32x4 mx;
#pragma unroll
    for (int e = 0; e < 4; ++e)
        mx[e] = fmaxf(fmaxf(sv0[e], sv1[e]), fmaxf(sv2[e], sv3[e]));
    red16_max4(mx);
#pragma unroll
    for (int e = 0; e < 4; ++e) {
        sv0[e] = __expf(sv0[e] - mx[e]);
        sv1[e] = __expf(sv1[e] - mx[e]);
        sv2[e] = __expf(sv2[e] - mx[e]);
        sv3[e] = __expf(sv3[e] - mx[e]);
    }
    f32x4 se = sv0 + sv1 + sv2 + sv3;
    red16_sum4(se);

    f32x4 at0 = q0 * (k0 + kbv[0]);
    f32x4 at1 = q1 * (k1 + kbv[1]);
    f32x4 at2 = q2 * (k2 + kbv[2]);
    f32x4 at3 = q3 * (k3 + kbv[3]);
    f32x4 nr = at0 * at0 + at1 * at1 + at2 * at2 + at3 * at3;
    red16_sum4(nr);

    f32x4 fac;
#pragma unroll
    for (int e = 0; e < 4; ++e)
        fac[e] = 1.0f / (fmaxf(sqrtf(nr[e]), 1e-8f) * se[e]);

#pragma unroll
    for (int e = 0; e < 4; ++e) {
        f16_t* rr = Rf + (rtb + quad * 4 + e) * RP16 + l15;
        rr[0]  = (f16_t)(at0[e] * sv0[e] * fac[e]);
        rr[16] = (f16_t)(at1[e] * sv1[e] * fac[e]);
        rr[32] = (f16_t)(at2[e] * sv2[e] * fac[e]);
        rr[48] = (f16_t)(at3[e] * sv3[e] * fac[e]);
    }
}

// 32-row d1 pass: h1 = relu(x @ d1 + b1), relay in-place
__device__ __forceinline__ void d1_rt(f16_t* __restrict__ Rf, const f16_t* __restrict__ wb,
                                      int l15, int quad, int rtb, f32x4 b1v)
{
    f16x8 x00 = *(const f16x8*)(Rf + (rtb + l15) * RP16 + quad * 8);
    f16x8 x01 = *(const f16x8*)(Rf + (rtb + l15) * RP16 + 32 + quad * 8);
    f16x8 x10 = *(const f16x8*)(Rf + (rtb + 16 + l15) * RP16 + quad * 8);
    f16x8 x11 = *(const f16x8*)(Rf + (rtb + 16 + l15) * RP16 + 32 + quad * 8);
    f32x4 h00 = {}, h01 = {}, h02 = {}, h03 = {};
    f32x4 h10 = {}, h11 = {}, h12 = {}, h13 = {};
    GEMML(wb, 0, x00, x01, x10, x11, h00, h10);
    GEMML(wb, 1, x00, x01, x10, x11, h01, h11);
    GEMML(wb, 2, x00, x01, x10, x11, h02, h12);
    GEMML(wb, 3, x00, x01, x10, x11, h03, h13);
#pragma unroll
    for (int e = 0; e < 4; ++e) {
        f16_t* r0 = Rf + (rtb + quad * 4 + e) * RP16 + l15;
        r0[0]  = (f16_t)fmaxf(h00[e] + b1v[0], 0.f);
        r0[16] = (f16_t)fmaxf(h01[e] + b1v[1], 0.f);
        r0[32] = (f16_t)fmaxf(h02[e] + b1v[2], 0.f);
        r0[48] = (f16_t)fmaxf(h03[e] + b1v[3], 0.f);
        f16_t* r1 = Rf + (rtb + 16 + quad * 4 + e) * RP16 + l15;
        r1[0]  = (f16_t)fmaxf(h10[e] + b1v[0], 0.f);
        r1[16] = (f16_t)fmaxf(h11[e] + b1v[1], 0.f);
        r1[32] = (f16_t)fmaxf(h12[e] + b1v[2], 0.f);
        r1[48] = (f16_t)fmaxf(h13[e] + b1v[3], 0.f);
    }
}

// 32-row d2 pass: h2 = relu(h1 @ d2 + b2), 32 cols
__device__ __forceinline__ void d2_rt(f16_t* __restrict__ Rf, const f16_t* __restrict__ wb,
                                      int l15, int quad, int rtb, float b20, float b21)
{
    f16x8 x00 = *(const f16x8*)(Rf + (rtb + l15) * RP16 + quad * 8);
    f16x8 x01 = *(const f16x8*)(Rf + (rtb + l15) * RP16 + 32 + quad * 8);
    f16x8 x10 = *(const f16x8*)(Rf + (rtb + 16 + l15) * RP16 + quad * 8);
    f16x8 x11 = *(const f16x8*)(Rf + (rtb + 16 + l15) * RP16 + 32 + quad * 8);
    f32x4 g00 = {}, g01 = {}, g10 = {}, g11 = {};
    GEMML(wb, 0, x00, x01, x10, x11, g00, g10);
    GEMML(wb, 1, x00, x01, x10, x11, g01, g11);
#pragma unroll
    for (int e = 0; e < 4; ++e) {
        f16_t* r0 = Rf + (rtb + quad * 4 + e) * RP16 + l15;
        r0[0]  = (f16_t)fmaxf(g00[e] + b20, 0.f);
        r0[16] = (f16_t)fmaxf(g01[e] + b21, 0.f);
        f16_t* r1 = Rf + (rtb + 16 + quad * 4 + e) * RP16 + l15;
        r1[0]  = (f16_t)fmaxf(g10[e] + b20, 0.f);
        r1[16] = (f16_t)fmaxf(g11[e] + b21, 0.f);
    }
}

// 32-row d3 pass: out = h2 @ d3 + b3 (K=32) -> two 16-row staged stores.
__device__ __forceinline__ void d3_rt(f16_t* __restrict__ Rf, float* __restrict__ Of,
                                      const char* __restrict__ d3b,
                                      int l15, int quad, int lane, int rtb,
                                      f32x4 b3v, float* __restrict__ obase)
{
    f16x8 a30 = *(const f16x8*)(Rf + (rtb + l15) * RP16 + quad * 8);
    f16x8 a31 = *(const f16x8*)(Rf + (rtb + 16 + l15) * RP16 + quad * 8);
    const int sw3 = ((l15 >> 1) & 3) << 4;
#pragma unroll
    for (int h = 0; h < 2; ++h) {
        const f16x8 a3 = h ? a31 : a30;
#pragma unroll
        for (int c = 0; c < 4; ++c) {
            int o3 = (16 * c + l15) * 64 + quad * 16;
            f16x8 bw = *(const f16x8*)(d3b + (o3 ^ sw3));
            f32x4 z = {};
            f32x4 o = mfma1(a3, bw, z);
#pragma unroll
            for (int e = 0; e < 4; ++e)
                Of[(quad * 4 + e) * OP32 + 16 * c + l15] = o[e] + b3v[c];
        }
#pragma unroll
        for (int i = 0; i < 4; ++i) {
            const int r4 = i * 4 + quad;
            f32x4 v = *(const f32x4*)(Of + r4 * OP32 + l15 * 4);
            *(f32x4*)(obase + rtb * 64 + h * 1024 + i * 256 + lane * 4) = v;
        }
    }
}

// ------- main: M=64/wave tile, 3-buffer single-barrier T pipeline, DPP sm --
__global__ __launch_bounds__(TPB, 2)   // natural regalloc; spill tripwire = WRITE_SIZE
void fused_mfma(const float* __restrict__ kv_in, const float* __restrict__ q_in,
                const float* __restrict__ keyB,  const float* __restrict__ valB,
                const float* __restrict__ d1B,   const float* __restrict__ d2B,
                const float* __restrict__ d3B,   const float* __restrict__ scale_p,
                const f16_t* __restrict__ wsf,   float* __restrict__ out)
{
    __shared__ __align__(16) unsigned char Slab[4][SLABB];   // 36864 B (wave-private)
    __shared__ __align__(16) float Qs[8][MT];                // 8192 B
    __shared__ __align__(16) f16_t WB[3][4096];              // 24576 B -> 69632 total (2 blk/CU)

    const int tid  = threadIdx.x;
    const int wv   = tid >> 6, lane = tid & 63;
    const int quad = lane >> 4, l15 = lane & 15;
    const int RB   = wv * 64;
    const long t0  = (long)blockIdx.x * MT;

    f16_t* __restrict__ Rf = (f16_t*)Slab[wv];
    float* __restrict__ Of = (float*)Slab[wv];

    // ---- kick off async DMA of T planes 0,1 FIRST (oldest in vmcnt queue) ----
    stage8k(wsf + OFF_T + 0 * 4096, WB[0], tid);
    stage8k(wsf + OFF_T + 1 * 4096, WB[1], tid);

    // ---- small params early (L2 loads overlap relay) ----
    f32x4 kbv, vbv, b1v, b3v;
#pragma unroll
    for (int c = 0; c < 4; ++c) {
        kbv[c] = keyB[16 * c + l15];  vbv[c] = valB[16 * c + l15];
        b1v[c] = d1B[16 * c + l15];   b3v[c] = d3B[16 * c + l15];
    }
    const float b20 = d2B[l15], b21 = d2B[16 + l15];
    const float sc = scale_p[0];

    // ---- coalesced kv staging -> fp16 relay, 64 rows/wave ----
    {
        const int r = lane >> 1, half = lane & 1;
#pragma unroll
        for (int s = 0; s < 2; ++s) {
            const float4* p4 = (const float4*)(kv_in + (t0 + RB + s * 32 + r) * 64 + half * 32);
            f16_t* dst = Rf + (s * 32 + r) * RP16 + half * 32;
#pragma unroll
            for (int b = 0; b < 4; ++b) {
                float4 f0 = p4[2 * b], f1 = p4[2 * b + 1];
                f16x8 h;
                h[0] = (f16_t)f0.x; h[1] = (f16_t)f0.y; h[2] = (f16_t)f0.z; h[3] = (f16_t)f0.w;
                h[4] = (f16_t)f1.x; h[5] = (f16_t)f1.y; h[6] = (f16_t)f1.z; h[7] = (f16_t)f1.w;
                *(f16x8*)(dst + 8 * b) = h;
            }
        }
    }
    // ---- q' -> Qs (all 64 lanes, 64 tokens/wave) ----
    {
        const float* qp = q_in + (t0 + RB + lane) * 7;
#pragma unroll
        for (int p = 0; p < 7; ++p) Qs[p][RB + lane] = qp[p];
        Qs[7][RB + lane] = 1.0f;
    }

    // ---- A-fragments: 4 row-tiles x 2 halves (named) ----
    f16x8 ah00 = *(const f16x8*)(Rf + l15 * RP16 + quad * 8);
    f16x8 ah01 = *(const f16x8*)(Rf + l15 * RP16 + 32 + quad * 8);
    f16x8 ah10 = *(const f16x8*)(Rf + (16 + l15) * RP16 + quad * 8);
    f16x8 ah11 = *(const f16x8*)(Rf + (16 + l15) * RP16 + 32 + quad * 8);
    f16x8 ah20 = *(const f16x8*)(Rf + (32 + l15) * RP16 + quad * 8);
    f16x8 ah21 = *(const f16x8*)(Rf + (32 + l15) * RP16 + 32 + quad * 8);
    f16x8 ah30 = *(const f16x8*)(Rf + (48 + l15) * RP16 + quad * 8);
    f16x8 ah31 = *(const f16x8*)(Rf + (48 + l15) * RP16 + 32 + quad * 8);

    // ---- T stage, 3-buffer pipeline, ONE barrier per plane ----
    // iter p: VMW2 (own plane-p loads done; only newest stage in flight);
    // BAR (all waves' plane-p contributions done AND all waves finished
    // reading plane p-1 -> safe to overwrite WB[(p+2)%3] == WB[(p-1)%3]).
    // Read WB[p%3] while staging WB[(p+2)%3]: disjoint (2 != 0 mod 3).
    f32x4 q00 = {}, q01 = {}, q02 = {}, q03 = {};
    f32x4 q10 = {}, q11 = {}, q12 = {}, q13 = {};
    f32x4 q20 = {}, q21 = {}, q22 = {}, q23 = {};
    f32x4 q30 = {}, q31 = {}, q32 = {}, q33 = {};
#pragma unroll 1
    for (int p = 0; p < 8; ++p) {
        const f16_t* tb = WB[p % 3];
        VMW2(); BAR();
        const f16_t* nsrc = (p < 6) ? (wsf + OFF_T + (p + 2) * 4096)
                                    : ((p == 6) ? (wsf + OFF_KEY) : (wsf + OFF_VAL));
        stage8k(nsrc, WB[(p + 2) % 3], tid);
        f32x4 qa0 = *(const f32x4*)&Qs[p][RB + quad * 4];
        f32x4 qa1 = *(const f32x4*)&Qs[p][RB + 16 + quad * 4];
        f32x4 qa2 = *(const f32x4*)&Qs[p][RB + 32 + quad * 4];
        f32x4 qa3 = *(const f32x4*)&Qs[p][RB + 48 + quad * 4];
        TCOL(tb, 0, qa0, qa1, qa2, qa3, q00, q10, q20, q30);
        TCOL(tb, 1, qa0, qa1, qa2, qa3, q01, q11, q21, q31);
        TCOL(tb, 2, qa0, qa1, qa2, qa3, q02, q12, q22, q32);
        TCOL(tb, 3, qa0, qa1, qa2, qa3, q03, q13, q23, q33);
    }
    VMW0(); BAR();   // KEY in WB[2], VAL in WB[0] ready (planes 8,9 mod 3)

    // d1 DMA issued NOW -> hides under the fronts (WB[1] is free: plane 7 consumed)
    stage8k(wsf + OFF_D1, WB[1], tid);

    // ---- fronts: 4 independent row-tiles (k|v + softmax + att + relay) ----
    front_rt(Rf, WB[2], WB[0], l15, quad, 0,  ah00, ah01, q00, q01, q02, q03, kbv, vbv, sc);
    front_rt(Rf, WB[2], WB[0], l15, quad, 16, ah10, ah11, q10, q11, q12, q13, kbv, vbv, sc);
    front_rt(Rf, WB[2], WB[0], l15, quad, 32, ah20, ah21, q20, q21, q22, q23, kbv, vbv, sc);
    front_rt(Rf, WB[2], WB[0], l15, quad, 48, ah30, ah31, q30, q31, q32, q33, kbv, vbv, sc);
    BAR();           // all waves done reading key/val panels
    stage4k_r128(wsf + OFF_D2, WB[2], tid);            // d2 -> WB[2][0:2048] (4KB)
    stage4k_r64 (wsf + OFF_D3, WB[2] + 2048, tid);     // d3 -> WB[2][2048:] (4KB, 64B rows)
    VMW0(); BAR();

    // ---- d-chain: two 32-row passes per layer (wave-private, no barriers) ----
    d1_rt(Rf, WB[1], l15, quad, 0,  b1v);
    d1_rt(Rf, WB[1], l15, quad, 32, b1v);
    d2_rt(Rf, WB[2], l15, quad, 0,  b20, b21);
    d2_rt(Rf, WB[2], l15, quad, 32, b20, b21);

    float* __restrict__ obase = out + (t0 + RB) * 64;
    const char* d3b = (const char*)(&WB[2][2048]);
    d3_rt(Rf, Of, d3b, l15, quad, lane, 0,  b3v, obase);
    d3_rt(Rf, Of, d3b, l15, quad, lane, 32, b3v, obase);
}

extern "C" void kernel_launch(void* const* d_in, const int* in_sizes, int n_in,
                              void* d_out, int out_size, void* d_ws, size_t ws_size,
                              hipStream_t stream) {
    (void)in_sizes; (void)n_in; (void)out_size; (void)ws_size;
    const float* kv_in = (const float*)d_in[0];
    const float* q_in  = (const float*)d_in[1];
    const float* keyW  = (const float*)d_in[2];
    const float* keyB  = (const float*)d_in[3];
    const float* valW  = (const float*)d_in[4];
    const float* valB  = (const float*)d_in[5];
    const float* TW    = (const float*)d_in[6];
    const float* TB    = (const float*)d_in[7];
    const float* d1W   = (const float*)d_in[8];
    const float* d1B   = (const float*)d_in[9];
    const float* d2W   = (const float*)d_in[10];
    const float* d2B   = (const float*)d_in[11];
    const float* d3W   = (const float*)d_in[12];
    const float* d3B   = (const float*)d_in[13];
    const float* scale = (const float*)d_in[14];
    f16_t* wsf = (f16_t*)d_ws;
    float* outp = (float*)d_out;

    prep_w<<<(WTOT + 255) / 256, 256, 0, stream>>>(keyW, valW, TW, TB, d1W, d2W, d3W, wsf);
    fused_mfma<<<NTOK / MT, TPB, 0, stream>>>(kv_in, q_in, keyB, valB,
                                              d1B, d2B, d3B, scale, wsf, outp);
}

// Round 6
// 128.202 us; speedup vs baseline: 1.0295x; 1.0295x over previous
//
#include <hip/hip_runtime.h>
#include <math.h>

typedef _Float16 f16_t;
typedef __attribute__((ext_vector_type(8))) _Float16 f16x8;
typedef __attribute__((ext_vector_type(4))) float f32x4;

#define NTOK 131072
#define MT   256      // tokens per block
#define TPB  256      // 4 waves; each wave owns 64 tokens (M=64 tile)
#define RP16 72       // relay pitch (f16)
#define OP32 68       // out-stage pitch (f32)
#define SLABB 9216    // per-wave slab: relay 64*72*2

// ws layout (f16 elems)
#define OFF_KEY 0
#define OFF_VAL 4096
#define OFF_T   8192
#define OFF_D1  40960
#define OFF_D2  45056
#define OFF_D3  47104
#define WTOT    49152

__device__ __forceinline__ f32x4 mfma1(f16x8 a, f16x8 b, f32x4 c) {
    return __builtin_amdgcn_mfma_f32_16x16x32_f16(a, b, c, 0, 0, 0);
}

// ---- DPP 16-lane butterfly reductions (VALU, no LDS round-trips) ----------
#define DPPF(x, C) __int_as_float(__builtin_amdgcn_update_dpp( \
    0, __float_as_int(x), (C), 0xF, 0xF, true))

__device__ __forceinline__ void red16_sum4(f32x4& x) {
#pragma unroll
    for (int e = 0; e < 4; ++e) {
        float v = x[e];
        v += DPPF(v, 0xB1);
        v += DPPF(v, 0x4E);
        v += DPPF(v, 0x141);
        v += DPPF(v, 0x140);
        x[e] = v;
    }
}
__device__ __forceinline__ void red16_max4(f32x4& x) {
#pragma unroll
    for (int e = 0; e < 4; ++e) {
        float v = x[e];
        v = fmaxf(v, DPPF(v, 0xB1));
        v = fmaxf(v, DPPF(v, 0x4E));
        v = fmaxf(v, DPPF(v, 0x141));
        v = fmaxf(v, DPPF(v, 0x140));
        x[e] = v;
    }
}

struct B2 { f16x8 b0, b1; };

// LDS B-fragment read, XOR-swizzled (128B-row panels). Proven conflict-clean in R3.
__device__ __forceinline__ B2 loadB_lds(const f16_t* __restrict__ b, int c, int l15, int quad) {
    const char* base = (const char*)b;
    int o0 = (16 * c + l15) * 128 + quad * 16;
    int sw = (l15 & 7) << 4;
    B2 r;
    r.b0 = *(const f16x8*)(base + (o0 ^ sw));
    r.b1 = *(const f16x8*)(base + ((o0 + 64) ^ sw));
    return r;
}

#define GEMML(buf, c, a00, a01, a10, a11, acc0, acc1) do {        \
    B2 Bf = loadB_lds((buf), (c), l15, quad);                      \
    acc0 = mfma1(a01, Bf.b1, mfma1(a00, Bf.b0, acc0));             \
    acc1 = mfma1(a11, Bf.b1, mfma1(a10, Bf.b0, acc1));             \
} while (0)

// async global->LDS DMA, 16B/lane; LDS dest linear (base + lane*16)
__device__ __forceinline__ void gl_lds16(const void* g, void* l) {
    __builtin_amdgcn_global_load_lds(
        (const __attribute__((address_space(1))) unsigned int*)g,
        (__attribute__((address_space(3))) unsigned int*)l, 16, 0, 0);
}

// Stage an 8KB 128B-row panel; swizzle applied as inverse perm on the GLOBAL src
// (both-sides-or-neither rule): LDS[row][col ^ ((row&7)<<4)] = G[row][col].
__device__ __forceinline__ void stage8k(const f16_t* __restrict__ gsrc, f16_t* lbuf, int tid) {
#pragma unroll
    for (int i = 0; i < 2; ++i) {
        int o = (i * 256 + tid) * 16;
        int g = o ^ (((o >> 7) & 7) << 4);
        gl_lds16((const char*)gsrc + g, (char*)lbuf + (o & ~1023));
    }
}
__device__ __forceinline__ void stage4k_r128(const f16_t* __restrict__ gsrc, f16_t* lbuf, int tid) {
    int o = tid * 16;
    int g = o ^ (((o >> 7) & 7) << 4);
    gl_lds16((const char*)gsrc + g, (char*)lbuf + (o & ~1023));
}
// 64B-row panel (d3): swizzle XORs bits 4-5 with row>>1
__device__ __forceinline__ void stage4k_r64(const f16_t* __restrict__ gsrc, f16_t* lbuf, int tid) {
    int o = tid * 16;
    int g = o ^ (((o >> 7) & 3) << 4);
    gl_lds16((const char*)gsrc + g, (char*)lbuf + (o & ~1023));
}

// counted vmcnt + raw barrier (NEVER __syncthreads: it drains vmcnt(0))
#define VMW2() asm volatile("s_waitcnt vmcnt(2)" ::: "memory")
#define VMW0() asm volatile("s_waitcnt vmcnt(0)" ::: "memory")
#define BAR()  do { __builtin_amdgcn_s_barrier(); asm volatile("" ::: "memory"); } while (0)

// ---------------- prep: transpose all weights into ws as fp16 --------------
__global__ __launch_bounds__(256)
void prep_w(const float* __restrict__ keyW, const float* __restrict__ valW,
            const float* __restrict__ TW,   const float* __restrict__ TB,
            const float* __restrict__ d1W,  const float* __restrict__ d2W,
            const float* __restrict__ d3W,  f16_t* __restrict__ wsf)
{
    int idx = blockIdx.x * 256 + threadIdx.x;
    if (idx >= WTOT) return;
    float src;
    if (idx < OFF_VAL) {
        int r = idx - OFF_KEY, n = r >> 6, j = r & 63;
        src = keyW[j * 64 + n];
    } else if (idx < OFF_T) {
        int r = idx - OFF_VAL, n = r >> 6, j = r & 63;
        src = valW[j * 64 + n];
    } else if (idx < OFF_D1) {
        int r = idx - OFF_T, p = r >> 12, q = r & 4095;
        src = (p < 7) ? TW[p * 4096 + q] : TB[q];
    } else if (idx < OFF_D2) {
        int r = idx - OFF_D1, n = r >> 6, j = r & 63;
        src = d1W[j * 64 + n];
    } else if (idx < OFF_D3) {
        int r = idx - OFF_D2, n = r >> 6, j = r & 63;
        src = d2W[j * 32 + n];
    } else {
        int r = idx - OFF_D3, n = r >> 5, j = r & 31;
        src = d3W[j * 64 + n];
    }
    wsf[idx] = (f16_t)src;
}

// per-row-tile front: k|v GEMM (LDS-staged) + softmax + att + normalize + relay.
__device__ __forceinline__ void front_rt(
    f16_t* __restrict__ Rf,
    const f16_t* __restrict__ keyb, const f16_t* __restrict__ valb,
    int l15, int quad, int rtb,
    f16x8 a0, f16x8 a1,
    f32x4 q0, f32x4 q1, f32x4 q2, f32x4 q3,
    f32x4 kbv, f32x4 vbv, float sc)
{
    f32x4 k0 = {}, k1 = {}, k2 = {}, k3 = {}, v0 = {}, v1 = {}, v2 = {}, v3 = {};
    { B2 B = loadB_lds(keyb, 0, l15, quad); k0 = mfma1(a1, B.b1, mfma1(a0, B.b0, k0)); }
    { B2 B = loadB_lds(keyb, 1, l15, quad); k1 = mfma1(a1, B.b1, mfma1(a0, B.b0, k1)); }
    { B2 B = loadB_lds(keyb, 2, l15, quad); k2 = mfma1(a1, B.b1, mfma1(a0, B.b0, k2)); }
    { B2 B = loadB_lds(keyb, 3, l15, quad); k3 = mfma1(a1, B.b1, mfma1(a0, B.b0, k3)); }
    { B2 B = loadB_lds(valb, 0, l15, quad); v0 = mfma1(a1, B.b1, mfma1(a0, B.b0, v0)); }
    { B2 B = loadB_lds(valb, 1, l15, quad); v1 = mfma1(a1, B.b1, mfma1(a0, B.b0, v1)); }
    { B2 B = loadB_lds(valb, 2, l15, quad); v2 = mfma1(a1, B.b1, mfma1(a0, B.b0, v2)); }
    { B2 B = loadB_lds(valb, 3, l15, quad); v3 = mfma1(a1, B.b1, mfma1(a0, B.b0, v3)); }

    f32x4 sv0 = (v0 + vbv[0]) * sc;
    f32x4 sv1 = (v1 + vbv[1]) * sc;
    f32x4 sv2 = (v2 + vbv[2]) * sc;
    f32x4 sv3 = (v3 + vbv[3]) * sc;

    f32x4 mx;
#pragma unroll
    for (int e = 0; e < 4; ++e)
        mx[e] = fmaxf(fmaxf(sv0[e], sv1[e]), fmaxf(sv2[e], sv3[e]));
    red16_max4(mx);
#pragma unroll
    for (int e = 0; e < 4; ++e) {
        sv0[e] = __expf(sv0[e] - mx[e]);
        sv1[e] = __expf(sv1[e] - mx[e]);
        sv2[e] = __expf(sv2[e] - mx[e]);
        sv3[e] = __expf(sv3[e] - mx[e]);
    }
    f32x4 se = sv0 + sv1 + sv2 + sv3;
    red16_sum4(se);

    f32x4 at0 = q0 * (k0 + kbv[0]);
    f32x4 at1 = q1 * (k1 + kbv[1]);
    f32x4 at2 = q2 * (k2 + kbv[2]);
    f32x4 at3 = q3 * (k3 + kbv[3]);
    f32x4 nr = at0 * at0 + at1 * at1 + at2 * at2 + at3 * at3;
    red16_sum4(nr);

    f32x4 fac;
#pragma unroll
    for (int e = 0; e < 4; ++e)
        fac[e] = 1.0f / (fmaxf(sqrtf(nr[e]), 1e-8f) * se[e]);

#pragma unroll
    for (int e = 0; e < 4; ++e) {
        f16_t* rr = Rf + (rtb + quad * 4 + e) * RP16 + l15;
        rr[0]  = (f16_t)(at0[e] * sv0[e] * fac[e]);
        rr[16] = (f16_t)(at1[e] * sv1[e] * fac[e]);
        rr[32] = (f16_t)(at2[e] * sv2[e] * fac[e]);
        rr[48] = (f16_t)(at3[e] * sv3[e] * fac[e]);
    }
}

// 32-row d1 pass: h1 = relu(x @ d1 + b1), relay in-place
__device__ __forceinline__ void d1_rt(f16_t* __restrict__ Rf, const f16_t* __restrict__ wb,
                                      int l15, int quad, int rtb, f32x4 b1v)
{
    f16x8 x00 = *(const f16x8*)(Rf + (rtb + l15) * RP16 + quad * 8);
    f16x8 x01 = *(const f16x8*)(Rf + (rtb + l15) * RP16 + 32 + quad * 8);
    f16x8 x10 = *(const f16x8*)(Rf + (rtb + 16 + l15) * RP16 + quad * 8);
    f16x8 x11 = *(const f16x8*)(Rf + (rtb + 16 + l15) * RP16 + 32 + quad * 8);
    f32x4 h00 = {}, h01 = {}, h02 = {}, h03 = {};
    f32x4 h10 = {}, h11 = {}, h12 = {}, h13 = {};
    GEMML(wb, 0, x00, x01, x10, x11, h00, h10);
    GEMML(wb, 1, x00, x01, x10, x11, h01, h11);
    GEMML(wb, 2, x00, x01, x10, x11, h02, h12);
    GEMML(wb, 3, x00, x01, x10, x11, h03, h13);
#pragma unroll
    for (int e = 0; e < 4; ++e) {
        f16_t* r0 = Rf + (rtb + quad * 4 + e) * RP16 + l15;
        r0[0]  = (f16_t)fmaxf(h00[e] + b1v[0], 0.f);
        r0[16] = (f16_t)fmaxf(h01[e] + b1v[1], 0.f);
        r0[32] = (f16_t)fmaxf(h02[e] + b1v[2], 0.f);
        r0[48] = (f16_t)fmaxf(h03[e] + b1v[3], 0.f);
        f16_t* r1 = Rf + (rtb + 16 + quad * 4 + e) * RP16 + l15;
        r1[0]  = (f16_t)fmaxf(h10[e] + b1v[0], 0.f);
        r1[16] = (f16_t)fmaxf(h11[e] + b1v[1], 0.f);
        r1[32] = (f16_t)fmaxf(h12[e] + b1v[2], 0.f);
        r1[48] = (f16_t)fmaxf(h13[e] + b1v[3], 0.f);
    }
}

// 32-row d2 pass: h2 = relu(h1 @ d2 + b2), 32 cols
__device__ __forceinline__ void d2_rt(f16_t* __restrict__ Rf, const f16_t* __restrict__ wb,
                                      int l15, int quad, int rtb, float b20, float b21)
{
    f16x8 x00 = *(const f16x8*)(Rf + (rtb + l15) * RP16 + quad * 8);
    f16x8 x01 = *(const f16x8*)(Rf + (rtb + l15) * RP16 + 32 + quad * 8);
    f16x8 x10 = *(const f16x8*)(Rf + (rtb + 16 + l15) * RP16 + quad * 8);
    f16x8 x11 = *(const f16x8*)(Rf + (rtb + 16 + l15) * RP16 + 32 + quad * 8);
    f32x4 g00 = {}, g01 = {}, g10 = {}, g11 = {};
    GEMML(wb, 0, x00, x01, x10, x11, g00, g10);
    GEMML(wb, 1, x00, x01, x10, x11, g01, g11);
#pragma unroll
    for (int e = 0; e < 4; ++e) {
        f16_t* r0 = Rf + (rtb + quad * 4 + e) * RP16 + l15;
        r0[0]  = (f16_t)fmaxf(g00[e] + b20, 0.f);
        r0[16] = (f16_t)fmaxf(g01[e] + b21, 0.f);
        f16_t* r1 = Rf + (rtb + 16 + quad * 4 + e) * RP16 + l15;
        r1[0]  = (f16_t)fmaxf(g10[e] + b20, 0.f);
        r1[16] = (f16_t)fmaxf(g11[e] + b21, 0.f);
    }
}

// 32-row d3 pass: out = h2 @ d3 + b3 (K=32) -> two 16-row staged stores.
__device__ __forceinline__ void d3_rt(f16_t* __restrict__ Rf, float* __restrict__ Of,
                                      const char* __restrict__ d3b,
                                      int l15, int quad, int lane, int rtb,
                                      f32x4 b3v, float* __restrict__ obase)
{
    f16x8 a30 = *(const f16x8*)(Rf + (rtb + l15) * RP16 + quad * 8);
    f16x8 a31 = *(const f16x8*)(Rf + (rtb + 16 + l15) * RP16 + quad * 8);
    const int sw3 = ((l15 >> 1) & 3) << 4;
#pragma unroll
    for (int h = 0; h < 2; ++h) {
        const f16x8 a3 = h ? a31 : a30;
#pragma unroll
        for (int c = 0; c < 4; ++c) {
            int o3 = (16 * c + l15) * 64 + quad * 16;
            f16x8 bw = *(const f16x8*)(d3b + (o3 ^ sw3));
            f32x4 z = {};
            f32x4 o = mfma1(a3, bw, z);
#pragma unroll
            for (int e = 0; e < 4; ++e)
                Of[(quad * 4 + e) * OP32 + 16 * c + l15] = o[e] + b3v[c];
        }
#pragma unroll
        for (int i = 0; i < 4; ++i) {
            const int r4 = i * 4 + quad;
            f32x4 v = *(const f32x4*)(Of + r4 * OP32 + l15 * 4);
            *(f32x4*)(obase + rtb * 64 + h * 1024 + i * 256 + lane * 4) = v;
        }
    }
}

// ------- main: T-stage as ONE K=512 GEMM (row-scaled A, MFMA accumulate) ---
__global__ __launch_bounds__(TPB, 2)   // natural regalloc; spill tripwire = WRITE_SIZE
void fused_mfma(const float* __restrict__ kv_in, const float* __restrict__ q_in,
                const float* __restrict__ keyB,  const float* __restrict__ valB,
                const float* __restrict__ d1B,   const float* __restrict__ d2B,
                const float* __restrict__ d3B,   const float* __restrict__ scale_p,
                const f16_t* __restrict__ wsf,   float* __restrict__ out)
{
    __shared__ __align__(16) unsigned char Slab[4][SLABB];   // 36864 B (wave-private)
    __shared__ __align__(16) f16_t Qs16[MT][8];              // 4096 B (f16 q'-table)
    __shared__ __align__(16) f16_t WB[3][4096];              // 24576 B -> 65536 total (2 blk/CU)

    const int tid  = threadIdx.x;
    const int wv   = tid >> 6, lane = tid & 63;
    const int quad = lane >> 4, l15 = lane & 15;
    const int RB   = wv * 64;
    const long t0  = (long)blockIdx.x * MT;

    f16_t* __restrict__ Rf = (f16_t*)Slab[wv];
    float* __restrict__ Of = (float*)Slab[wv];

    // ---- kick off async DMA of T planes 0,1 FIRST (oldest in vmcnt queue) ----
    stage8k(wsf + OFF_T + 0 * 4096, WB[0], tid);
    stage8k(wsf + OFF_T + 1 * 4096, WB[1], tid);

    // ---- small params early (L2 loads overlap relay) ----
    f32x4 kbv, vbv, b1v, b3v;
#pragma unroll
    for (int c = 0; c < 4; ++c) {
        kbv[c] = keyB[16 * c + l15];  vbv[c] = valB[16 * c + l15];
        b1v[c] = d1B[16 * c + l15];   b3v[c] = d3B[16 * c + l15];
    }
    const float b20 = d2B[l15], b21 = d2B[16 + l15];
    const float sc = scale_p[0];

    // ---- coalesced kv staging -> fp16 relay, 64 rows/wave ----
    {
        const int r = lane >> 1, half = lane & 1;
#pragma unroll
        for (int s = 0; s < 2; ++s) {
            const float4* p4 = (const float4*)(kv_in + (t0 + RB + s * 32 + r) * 64 + half * 32);
            f16_t* dst = Rf + (s * 32 + r) * RP16 + half * 32;
#pragma unroll
            for (int b = 0; b < 4; ++b) {
                float4 f0 = p4[2 * b], f1 = p4[2 * b + 1];
                f16x8 h;
                h[0] = (f16_t)f0.x; h[1] = (f16_t)f0.y; h[2] = (f16_t)f0.z; h[3] = (f16_t)f0.w;
                h[4] = (f16_t)f1.x; h[5] = (f16_t)f1.y; h[6] = (f16_t)f1.z; h[7] = (f16_t)f1.w;
                *(f16x8*)(dst + 8 * b) = h;
            }
        }
    }
    // ---- q' -> Qs16 as f16 [token][plane], one b128 write per token ----
    {
        const float* qp = q_in + (t0 + RB + lane) * 7;
        f16x8 qh;
#pragma unroll
        for (int p = 0; p < 7; ++p) qh[p] = (f16_t)qp[p];
        qh[7] = (f16_t)1.0f;
        *(f16x8*)&Qs16[RB + lane][0] = qh;
    }

    // ---- A-fragments: 4 row-tiles x 2 halves (named) ----
    f16x8 ah00 = *(const f16x8*)(Rf + l15 * RP16 + quad * 8);
    f16x8 ah01 = *(const f16x8*)(Rf + l15 * RP16 + 32 + quad * 8);
    f16x8 ah10 = *(const f16x8*)(Rf + (16 + l15) * RP16 + quad * 8);
    f16x8 ah11 = *(const f16x8*)(Rf + (16 + l15) * RP16 + 32 + quad * 8);
    f16x8 ah20 = *(const f16x8*)(Rf + (32 + l15) * RP16 + quad * 8);
    f16x8 ah21 = *(const f16x8*)(Rf + (32 + l15) * RP16 + 32 + quad * 8);
    f16x8 ah30 = *(const f16x8*)(Rf + (48 + l15) * RP16 + quad * 8);
    f16x8 ah31 = *(const f16x8*)(Rf + (48 + l15) * RP16 + 32 + quad * 8);

    // ---- T stage as one K=512 GEMM: q = sum_p (diag(q'_p) KV) @ T_p^T ----
    // Per-row scalar q'_p[row] folded into the A-frags (all 8 lane-elements are
    // row l15) as an f16 splat-multiply; MFMA accumulates across all planes.
    // NO MFMA->VALU round-trip in the loop-carried path.
    f32x4 q00 = {}, q01 = {}, q02 = {}, q03 = {};
    f32x4 q10 = {}, q11 = {}, q12 = {}, q13 = {};
    f32x4 q20 = {}, q21 = {}, q22 = {}, q23 = {};
    f32x4 q30 = {}, q31 = {}, q32 = {}, q33 = {};
#pragma unroll 1
    for (int p = 0; p < 8; ++p) {
        const f16_t* tb = WB[p % 3];
        VMW2(); BAR();
        const f16_t* nsrc = (p < 6) ? (wsf + OFF_T + (p + 2) * 4096)
                                    : ((p == 6) ? (wsf + OFF_KEY) : (wsf + OFF_VAL));
        stage8k(nsrc, WB[(p + 2) % 3], tid);
        // per-row-tile scale (ds_read_u16, quad-broadcast, conflict-free)
        f16_t s0 = Qs16[RB + l15][p];
        f16_t s1 = Qs16[RB + 16 + l15][p];
        f16_t s2 = Qs16[RB + 32 + l15][p];
        f16_t s3 = Qs16[RB + 48 + l15][p];
        f16x8 w0 = {s0, s0, s0, s0, s0, s0, s0, s0};
        f16x8 w1 = {s1, s1, s1, s1, s1, s1, s1, s1};
        f16x8 w2 = {s2, s2, s2, s2, s2, s2, s2, s2};
        f16x8 w3 = {s3, s3, s3, s3, s3, s3, s3, s3};
        f16x8 sa00 = ah00 * w0, sa01 = ah01 * w0;
        f16x8 sa10 = ah10 * w1, sa11 = ah11 * w1;
        f16x8 sa20 = ah20 * w2, sa21 = ah21 * w2;
        f16x8 sa30 = ah30 * w3, sa31 = ah31 * w3;
        { B2 B = loadB_lds(tb, 0, l15, quad);
          q00 = mfma1(sa01, B.b1, mfma1(sa00, B.b0, q00));
          q10 = mfma1(sa11, B.b1, mfma1(sa10, B.b0, q10));
          q20 = mfma1(sa21, B.b1, mfma1(sa20, B.b0, q20));
          q30 = mfma1(sa31, B.b1, mfma1(sa30, B.b0, q30)); }
        { B2 B = loadB_lds(tb, 1, l15, quad);
          q01 = mfma1(sa01, B.b1, mfma1(sa00, B.b0, q01));
          q11 = mfma1(sa11, B.b1, mfma1(sa10, B.b0, q11));
          q21 = mfma1(sa21, B.b1, mfma1(sa20, B.b0, q21));
          q31 = mfma1(sa31, B.b1, mfma1(sa30, B.b0, q31)); }
        { B2 B = loadB_lds(tb, 2, l15, quad);
          q02 = mfma1(sa01, B.b1, mfma1(sa00, B.b0, q02));
          q12 = mfma1(sa11, B.b1, mfma1(sa10, B.b0, q12));
          q22 = mfma1(sa21, B.b1, mfma1(sa20, B.b0, q22));
          q32 = mfma1(sa31, B.b1, mfma1(sa30, B.b0, q32)); }
        { B2 B = loadB_lds(tb, 3, l15, quad);
          q03 = mfma1(sa01, B.b1, mfma1(sa00, B.b0, q03));
          q13 = mfma1(sa11, B.b1, mfma1(sa10, B.b0, q13));
          q23 = mfma1(sa21, B.b1, mfma1(sa20, B.b0, q23));
          q33 = mfma1(sa31, B.b1, mfma1(sa30, B.b0, q33)); }
    }
    VMW0(); BAR();   // KEY in WB[2], VAL in WB[0] ready (planes 8,9 mod 3)

    // d1 DMA issued NOW -> hides under the fronts (WB[1] free: plane 7 consumed)
    stage8k(wsf + OFF_D1, WB[1], tid);

    // ---- fronts: 4 independent row-tiles (k|v + softmax + att + relay) ----
    front_rt(Rf, WB[2], WB[0], l15, quad, 0,  ah00, ah01, q00, q01, q02, q03, kbv, vbv, sc);
    front_rt(Rf, WB[2], WB[0], l15, quad, 16, ah10, ah11, q10, q11, q12, q13, kbv, vbv, sc);
    front_rt(Rf, WB[2], WB[0], l15, quad, 32, ah20, ah21, q20, q21, q22, q23, kbv, vbv, sc);
    front_rt(Rf, WB[2], WB[0], l15, quad, 48, ah30, ah31, q30, q31, q32, q33, kbv, vbv, sc);
    BAR();           // all waves done reading key/val panels
    stage4k_r128(wsf + OFF_D2, WB[2], tid);            // d2 -> WB[2][0:2048] (4KB)
    stage4k_r64 (wsf + OFF_D3, WB[2] + 2048, tid);     // d3 -> WB[2][2048:] (4KB, 64B rows)
    VMW0(); BAR();

    // ---- d-chain: two 32-row passes per layer (wave-private, no barriers) ----
    d1_rt(Rf, WB[1], l15, quad, 0,  b1v);
    d1_rt(Rf, WB[1], l15, quad, 32, b1v);
    d2_rt(Rf, WB[2], l15, quad, 0,  b20, b21);
    d2_rt(Rf, WB[2], l15, quad, 32, b20, b21);

    float* __restrict__ obase = out + (t0 + RB) * 64;
    const char* d3b = (const char*)(&WB[2][2048]);
    d3_rt(Rf, Of, d3b, l15, quad, lane, 0,  b3v, obase);
    d3_rt(Rf, Of, d3b, l15, quad, lane, 32, b3v, obase);
}

extern "C" void kernel_launch(void* const* d_in, const int* in_sizes, int n_in,
                              void* d_out, int out_size, void* d_ws, size_t ws_size,
                              hipStream_t stream) {
    (void)in_sizes; (void)n_in; (void)out_size; (void)ws_size;
    const float* kv_in = (const float*)d_in[0];
    const float* q_in  = (const float*)d_in[1];
    const float* keyW  = (const float*)d_in[2];
    const float* keyB  = (const float*)d_in[3];
    const float* valW  = (const float*)d_in[4];
    const float* valB  = (const float*)d_in[5];
    const float* TW    = (const float*)d_in[6];
    const float* TB    = (const float*)d_in[7];
    const float* d1W   = (const float*)d_in[8];
    const float* d1B   = (const float*)d_in[9];
    const float* d2W   = (const float*)d_in[10];
    const float* d2B   = (const float*)d_in[11];
    const float* d3W   = (const float*)d_in[12];
    const float* d3B   = (const float*)d_in[13];
    const float* scale = (const float*)d_in[14];
    f16_t* wsf = (f16_t*)d_ws;
    float* outp = (float*)d_out;

    prep_w<<<(WTOT + 255) / 256, 256, 0, stream>>>(keyW, valW, TW, TB, d1W, d2W, d3W, wsf);
    fused_mfma<<<NTOK / MT, TPB, 0, stream>>>(kv_in, q_in, keyB, valB,
                                              d1B, d2B, d3B, scale, wsf, outp);
}

// Round 7
// 127.045 us; speedup vs baseline: 1.0389x; 1.0091x over previous
//
#include <hip/hip_runtime.h>
#include <math.h>

typedef _Float16 f16_t;
typedef __attribute__((ext_vector_type(8))) _Float16 f16x8;
typedef __attribute__((ext_vector_type(4))) float f32x4;

#define NTOK 131072
#define MT   128      // tokens per block
#define TPB  128      // 2 waves; each wave owns 64 tokens (M=64 tile)
#define RP16 72       // relay pitch (f16)
#define OP32 68       // out-stage pitch (f32)
#define SLABB 9216    // per-wave slab: relay 64*72*2

// ws layout (f16 elems)
#define OFF_KEY 0
#define OFF_VAL 4096
#define OFF_T   8192
#define OFF_D1  40960
#define OFF_D2  45056
#define OFF_D3  47104
#define WTOT    49152

__device__ __forceinline__ f32x4 mfma1(f16x8 a, f16x8 b, f32x4 c) {
    return __builtin_amdgcn_mfma_f32_16x16x32_f16(a, b, c, 0, 0, 0);
}

// ---- DPP 16-lane butterfly reductions (VALU, no LDS round-trips) ----------
#define DPPF(x, C) __int_as_float(__builtin_amdgcn_update_dpp( \
    0, __float_as_int(x), (C), 0xF, 0xF, true))

__device__ __forceinline__ void red16_sum4(f32x4& x) {
#pragma unroll
    for (int e = 0; e < 4; ++e) {
        float v = x[e];
        v += DPPF(v, 0xB1);
        v += DPPF(v, 0x4E);
        v += DPPF(v, 0x141);
        v += DPPF(v, 0x140);
        x[e] = v;
    }
}
__device__ __forceinline__ void red16_max4(f32x4& x) {
#pragma unroll
    for (int e = 0; e < 4; ++e) {
        float v = x[e];
        v = fmaxf(v, DPPF(v, 0xB1));
        v = fmaxf(v, DPPF(v, 0x4E));
        v = fmaxf(v, DPPF(v, 0x141));
        v = fmaxf(v, DPPF(v, 0x140));
        x[e] = v;
    }
}

struct B2 { f16x8 b0, b1; };

// LDS B-fragment read, XOR-swizzled (128B-row panels). Proven conflict-clean in R3.
__device__ __forceinline__ B2 loadB_lds(const f16_t* __restrict__ b, int c, int l15, int quad) {
    const char* base = (const char*)b;
    int o0 = (16 * c + l15) * 128 + quad * 16;
    int sw = (l15 & 7) << 4;
    B2 r;
    r.b0 = *(const f16x8*)(base + (o0 ^ sw));
    r.b1 = *(const f16x8*)(base + ((o0 + 64) ^ sw));
    return r;
}

#define GEMML(buf, c, a00, a01, a10, a11, acc0, acc1) do {        \
    B2 Bf = loadB_lds((buf), (c), l15, quad);                      \
    acc0 = mfma1(a01, Bf.b1, mfma1(a00, Bf.b0, acc0));             \
    acc1 = mfma1(a11, Bf.b1, mfma1(a10, Bf.b0, acc1));             \
} while (0)

// async global->LDS DMA, 16B/lane; LDS dest = wave-uniform base + lane*16
__device__ __forceinline__ void gl_lds16(const void* g, void* l) {
    __builtin_amdgcn_global_load_lds(
        (const __attribute__((address_space(1))) unsigned int*)g,
        (__attribute__((address_space(3))) unsigned int*)l, 16, 0, 0);
}

// Stage an 8KB 128B-row panel (TPB=128 -> 4 loads/thread). Swizzle applied as
// inverse perm on the GLOBAL src: LDS[row][col ^ ((row&7)<<4)] = G[row][col].
// (o & ~1023) = wave-uniform 1KB segment base (64 lanes x 16B).
__device__ __forceinline__ void stage8k(const f16_t* __restrict__ gsrc, f16_t* lbuf, int tid) {
#pragma unroll
    for (int i = 0; i < 4; ++i) {
        int o = (i * TPB + tid) * 16;
        int g = o ^ (((o >> 7) & 7) << 4);
        gl_lds16((const char*)gsrc + g, (char*)lbuf + (o & ~1023));
    }
}
__device__ __forceinline__ void stage4k_r128(const f16_t* __restrict__ gsrc, f16_t* lbuf, int tid) {
#pragma unroll
    for (int i = 0; i < 2; ++i) {
        int o = (i * TPB + tid) * 16;
        int g = o ^ (((o >> 7) & 7) << 4);
        gl_lds16((const char*)gsrc + g, (char*)lbuf + (o & ~1023));
    }
}
// 64B-row panel (d3): swizzle XORs bits 4-5 with row>>1
__device__ __forceinline__ void stage4k_r64(const f16_t* __restrict__ gsrc, f16_t* lbuf, int tid) {
#pragma unroll
    for (int i = 0; i < 2; ++i) {
        int o = (i * TPB + tid) * 16;
        int g = o ^ (((o >> 7) & 3) << 4);
        gl_lds16((const char*)gsrc + g, (char*)lbuf + (o & ~1023));
    }
}

// counted vmcnt + raw barrier (NEVER __syncthreads: it drains vmcnt(0))
#define VMW4() asm volatile("s_waitcnt vmcnt(4)" ::: "memory")
#define VMW0() asm volatile("s_waitcnt vmcnt(0)" ::: "memory")
#define BAR()  do { __builtin_amdgcn_s_barrier(); asm volatile("" ::: "memory"); } while (0)

// ---------------- prep: transpose all weights into ws as fp16 --------------
__global__ __launch_bounds__(256)
void prep_w(const float* __restrict__ keyW, const float* __restrict__ valW,
            const float* __restrict__ TW,   const float* __restrict__ TB,
            const float* __restrict__ d1W,  const float* __restrict__ d2W,
            const float* __restrict__ d3W,  f16_t* __restrict__ wsf)
{
    int idx = blockIdx.x * 256 + threadIdx.x;
    if (idx >= WTOT) return;
    float src;
    if (idx < OFF_VAL) {
        int r = idx - OFF_KEY, n = r >> 6, j = r & 63;
        src = keyW[j * 64 + n];
    } else if (idx < OFF_T) {
        int r = idx - OFF_VAL, n = r >> 6, j = r & 63;
        src = valW[j * 64 + n];
    } else if (idx < OFF_D1) {
        int r = idx - OFF_T, p = r >> 12, q = r & 4095;
        src = (p < 7) ? TW[p * 4096 + q] : TB[q];
    } else if (idx < OFF_D2) {
        int r = idx - OFF_D1, n = r >> 6, j = r & 63;
        src = d1W[j * 64 + n];
    } else if (idx < OFF_D3) {
        int r = idx - OFF_D2, n = r >> 6, j = r & 63;
        src = d2W[j * 32 + n];
    } else {
        int r = idx - OFF_D3, n = r >> 5, j = r & 31;
        src = d3W[j * 64 + n];
    }
    wsf[idx] = (f16_t)src;
}

// per-row-tile front: k|v GEMM (LDS-staged) + softmax + att + normalize + relay.
__device__ __forceinline__ void front_rt(
    f16_t* __restrict__ Rf,
    const f16_t* __restrict__ keyb, const f16_t* __restrict__ valb,
    int l15, int quad, int rtb,
    f16x8 a0, f16x8 a1,
    f32x4 q0, f32x4 q1, f32x4 q2, f32x4 q3,
    f32x4 kbv, f32x4 vbv, float sc)
{
    f32x4 k0 = {}, k1 = {}, k2 = {}, k3 = {}, v0 = {}, v1 = {}, v2 = {}, v3 = {};
    { B2 B = loadB_lds(keyb, 0, l15, quad); k0 = mfma1(a1, B.b1, mfma1(a0, B.b0, k0)); }
    { B2 B = loadB_lds(keyb, 1, l15, quad); k1 = mfma1(a1, B.b1, mfma1(a0, B.b0, k1)); }
    { B2 B = loadB_lds(keyb, 2, l15, quad); k2 = mfma1(a1, B.b1, mfma1(a0, B.b0, k2)); }
    { B2 B = loadB_lds(keyb, 3, l15, quad); k3 = mfma1(a1, B.b1, mfma1(a0, B.b0, k3)); }
    { B2 B = loadB_lds(valb, 0, l15, quad); v0 = mfma1(a1, B.b1, mfma1(a0, B.b0, v0)); }
    { B2 B = loadB_lds(valb, 1, l15, quad); v1 = mfma1(a1, B.b1, mfma1(a0, B.b0, v1)); }
    { B2 B = loadB_lds(valb, 2, l15, quad); v2 = mfma1(a1, B.b1, mfma1(a0, B.b0, v2)); }
    { B2 B = loadB_lds(valb, 3, l15, quad); v3 = mfma1(a1, B.b1, mfma1(a0, B.b0, v3)); }

    f32x4 sv0 = (v0 + vbv[0]) * sc;
    f32x4 sv1 = (v1 + vbv[1]) * sc;
    f32x4 sv2 = (v2 + vbv[2]) * sc;
    f32x4 sv3 = (v3 + vbv[3]) * sc;

    f32x4 mx;
#pragma unroll
    for (int e = 0; e < 4; ++e)
        mx[e] = fmaxf(fmaxf(sv0[e], sv1[e]), fmaxf(sv2[e], sv3[e]));
    red16_max4(mx);
#pragma unroll
    for (int e = 0; e < 4; ++e) {
        sv0[e] = __expf(sv0[e] - mx[e]);
        sv1[e] = __expf(sv1[e] - mx[e]);
        sv2[e] = __expf(sv2[e] - mx[e]);
        sv3[e] = __expf(sv3[e] - mx[e]);
    }
    f32x4 se = sv0 + sv1 + sv2 + sv3;
    red16_sum4(se);

    f32x4 at0 = q0 * (k0 + kbv[0]);
    f32x4 at1 = q1 * (k1 + kbv[1]);
    f32x4 at2 = q2 * (k2 + kbv[2]);
    f32x4 at3 = q3 * (k3 + kbv[3]);
    f32x4 nr = at0 * at0 + at1 * at1 + at2 * at2 + at3 * at3;
    red16_sum4(nr);

    f32x4 fac;
#pragma unroll
    for (int e = 0; e < 4; ++e)
        fac[e] = 1.0f / (fmaxf(sqrtf(nr[e]), 1e-8f) * se[e]);

#pragma unroll
    for (int e = 0; e < 4; ++e) {
        f16_t* rr = Rf + (rtb + quad * 4 + e) * RP16 + l15;
        rr[0]  = (f16_t)(at0[e] * sv0[e] * fac[e]);
        rr[16] = (f16_t)(at1[e] * sv1[e] * fac[e]);
        rr[32] = (f16_t)(at2[e] * sv2[e] * fac[e]);
        rr[48] = (f16_t)(at3[e] * sv3[e] * fac[e]);
    }
}

// 32-row d1 pass: h1 = relu(x @ d1 + b1), relay in-place
__device__ __forceinline__ void d1_rt(f16_t* __restrict__ Rf, const f16_t* __restrict__ wb,
                                      int l15, int quad, int rtb, f32x4 b1v)
{
    f16x8 x00 = *(const f16x8*)(Rf + (rtb + l15) * RP16 + quad * 8);
    f16x8 x01 = *(const f16x8*)(Rf + (rtb + l15) * RP16 + 32 + quad * 8);
    f16x8 x10 = *(const f16x8*)(Rf + (rtb + 16 + l15) * RP16 + quad * 8);
    f16x8 x11 = *(const f16x8*)(Rf + (rtb + 16 + l15) * RP16 + 32 + quad * 8);
    f32x4 h00 = {}, h01 = {}, h02 = {}, h03 = {};
    f32x4 h10 = {}, h11 = {}, h12 = {}, h13 = {};
    GEMML(wb, 0, x00, x01, x10, x11, h00, h10);
    GEMML(wb, 1, x00, x01, x10, x11, h01, h11);
    GEMML(wb, 2, x00, x01, x10, x11, h02, h12);
    GEMML(wb, 3, x00, x01, x10, x11, h03, h13);
#pragma unroll
    for (int e = 0; e < 4; ++e) {
        f16_t* r0 = Rf + (rtb + quad * 4 + e) * RP16 + l15;
        r0[0]  = (f16_t)fmaxf(h00[e] + b1v[0], 0.f);
        r0[16] = (f16_t)fmaxf(h01[e] + b1v[1], 0.f);
        r0[32] = (f16_t)fmaxf(h02[e] + b1v[2], 0.f);
        r0[48] = (f16_t)fmaxf(h03[e] + b1v[3], 0.f);
        f16_t* r1 = Rf + (rtb + 16 + quad * 4 + e) * RP16 + l15;
        r1[0]  = (f16_t)fmaxf(h10[e] + b1v[0], 0.f);
        r1[16] = (f16_t)fmaxf(h11[e] + b1v[1], 0.f);
        r1[32] = (f16_t)fmaxf(h12[e] + b1v[2], 0.f);
        r1[48] = (f16_t)fmaxf(h13[e] + b1v[3], 0.f);
    }
}

// 32-row d2 pass: h2 = relu(h1 @ d2 + b2), 32 cols
__device__ __forceinline__ void d2_rt(f16_t* __restrict__ Rf, const f16_t* __restrict__ wb,
                                      int l15, int quad, int rtb, float b20, float b21)
{
    f16x8 x00 = *(const f16x8*)(Rf + (rtb + l15) * RP16 + quad * 8);
    f16x8 x01 = *(const f16x8*)(Rf + (rtb + l15) * RP16 + 32 + quad * 8);
    f16x8 x10 = *(const f16x8*)(Rf + (rtb + 16 + l15) * RP16 + quad * 8);
    f16x8 x11 = *(const f16x8*)(Rf + (rtb + 16 + l15) * RP16 + 32 + quad * 8);
    f32x4 g00 = {}, g01 = {}, g10 = {}, g11 = {};
    GEMML(wb, 0, x00, x01, x10, x11, g00, g10);
    GEMML(wb, 1, x00, x01, x10, x11, g01, g11);
#pragma unroll
    for (int e = 0; e < 4; ++e) {
        f16_t* r0 = Rf + (rtb + quad * 4 + e) * RP16 + l15;
        r0[0]  = (f16_t)fmaxf(g00[e] + b20, 0.f);
        r0[16] = (f16_t)fmaxf(g01[e] + b21, 0.f);
        f16_t* r1 = Rf + (rtb + 16 + quad * 4 + e) * RP16 + l15;
        r1[0]  = (f16_t)fmaxf(g10[e] + b20, 0.f);
        r1[16] = (f16_t)fmaxf(g11[e] + b21, 0.f);
    }
}

// 32-row d3 pass: out = h2 @ d3 + b3 (K=32) -> two 16-row staged stores.
// Of region (<=4352B) is disjoint from rtb=32's A-rows (bytes >=4608).
__device__ __forceinline__ void d3_rt(f16_t* __restrict__ Rf, float* __restrict__ Of,
                                      const char* __restrict__ d3b,
                                      int l15, int quad, int lane, int rtb,
                                      f32x4 b3v, float* __restrict__ obase)
{
    f16x8 a30 = *(const f16x8*)(Rf + (rtb + l15) * RP16 + quad * 8);
    f16x8 a31 = *(const f16x8*)(Rf + (rtb + 16 + l15) * RP16 + quad * 8);
    const int sw3 = ((l15 >> 1) & 3) << 4;
#pragma unroll
    for (int h = 0; h < 2; ++h) {
        const f16x8 a3 = h ? a31 : a30;
#pragma unroll
        for (int c = 0; c < 4; ++c) {
            int o3 = (16 * c + l15) * 64 + quad * 16;
            f16x8 bw = *(const f16x8*)(d3b + (o3 ^ sw3));
            f32x4 z = {};
            f32x4 o = mfma1(a3, bw, z);
#pragma unroll
            for (int e = 0; e < 4; ++e)
                Of[(quad * 4 + e) * OP32 + 16 * c + l15] = o[e] + b3v[c];
        }
#pragma unroll
        for (int i = 0; i < 4; ++i) {
            const int r4 = i * 4 + quad;
            f32x4 v = *(const f32x4*)(Of + r4 * OP32 + l15 * 4);
            *(f32x4*)(obase + rtb * 64 + h * 1024 + i * 256 + lane * 4) = v;
        }
    }
}

// ------- main: MT=128/TPB=128 (4 independent blocks/CU, 2-wave barriers) ---
// Same 8 waves/CU as MT=256 but 4 decorrelated block instances: prologue DMA,
// T-loop, fronts, d-chain of different blocks overlap on the SIMDs.
__global__ __launch_bounds__(TPB, 2)   // natural regalloc; spill tripwire = WRITE_SIZE
void fused_mfma(const float* __restrict__ kv_in, const float* __restrict__ q_in,
                const float* __restrict__ keyB,  const float* __restrict__ valB,
                const float* __restrict__ d1B,   const float* __restrict__ d2B,
                const float* __restrict__ d3B,   const float* __restrict__ scale_p,
                const f16_t* __restrict__ wsf,   float* __restrict__ out)
{
    __shared__ __align__(16) unsigned char Slab[2][SLABB];   // 18432 B (wave-private)
    __shared__ __align__(16) f16_t Qs16[MT][8];              // 2048 B (f16 q'-table)
    __shared__ __align__(16) f16_t WB[2][4096];              // 16384 B -> 36864 total (4 blk/CU)

    const int tid  = threadIdx.x;
    const int wv   = tid >> 6, lane = tid & 63;
    const int quad = lane >> 4, l15 = lane & 15;
    const int RB   = wv * 64;
    const long t0  = (long)blockIdx.x * MT;

    f16_t* __restrict__ Rf = (f16_t*)Slab[wv];
    float* __restrict__ Of = (float*)Slab[wv];

    // ---- relay FIRST (oldest in vmcnt queue: its drain no longer forced to
    // wait on weight DMA), then q', params, THEN the T-plane stages ----
    {
        const int r = lane >> 1, half = lane & 1;
#pragma unroll
        for (int s = 0; s < 2; ++s) {
            const float4* p4 = (const float4*)(kv_in + (t0 + RB + s * 32 + r) * 64 + half * 32);
            f16_t* dst = Rf + (s * 32 + r) * RP16 + half * 32;
#pragma unroll
            for (int b = 0; b < 4; ++b) {
                float4 f0 = p4[2 * b], f1 = p4[2 * b + 1];
                f16x8 h;
                h[0] = (f16_t)f0.x; h[1] = (f16_t)f0.y; h[2] = (f16_t)f0.z; h[3] = (f16_t)f0.w;
                h[4] = (f16_t)f1.x; h[5] = (f16_t)f1.y; h[6] = (f16_t)f1.z; h[7] = (f16_t)f1.w;
                *(f16x8*)(dst + 8 * b) = h;
            }
        }
    }
    // q' -> Qs16 as f16 [token][plane] (wave-private rows: no barrier needed)
    {
        const float* qp = q_in + (t0 + RB + lane) * 7;
        f16x8 qh;
#pragma unroll
        for (int p = 0; p < 7; ++p) qh[p] = (f16_t)qp[p];
        qh[7] = (f16_t)1.0f;
        *(f16x8*)&Qs16[RB + lane][0] = qh;
    }
    // small params (L2 hits, consumed late)
    f32x4 kbv, vbv, b1v, b3v;
#pragma unroll
    for (int c = 0; c < 4; ++c) {
        kbv[c] = keyB[16 * c + l15];  vbv[c] = valB[16 * c + l15];
        b1v[c] = d1B[16 * c + l15];   b3v[c] = d3B[16 * c + l15];
    }
    const float b20 = d2B[l15], b21 = d2B[16 + l15];
    const float sc = scale_p[0];

    // async DMA of T planes 0,1 (newest in queue -> VMW4 at p=0 waits T0 only)
    stage8k(wsf + OFF_T + 0 * 4096, WB[0], tid);
    stage8k(wsf + OFF_T + 1 * 4096, WB[1], tid);

    // ---- A-fragments: 4 row-tiles x 2 halves (named) ----
    f16x8 ah00 = *(const f16x8*)(Rf + l15 * RP16 + quad * 8);
    f16x8 ah01 = *(const f16x8*)(Rf + l15 * RP16 + 32 + quad * 8);
    f16x8 ah10 = *(const f16x8*)(Rf + (16 + l15) * RP16 + quad * 8);
    f16x8 ah11 = *(const f16x8*)(Rf + (16 + l15) * RP16 + 32 + quad * 8);
    f16x8 ah20 = *(const f16x8*)(Rf + (32 + l15) * RP16 + quad * 8);
    f16x8 ah21 = *(const f16x8*)(Rf + (32 + l15) * RP16 + 32 + quad * 8);
    f16x8 ah30 = *(const f16x8*)(Rf + (48 + l15) * RP16 + quad * 8);
    f16x8 ah31 = *(const f16x8*)(Rf + (48 + l15) * RP16 + 32 + quad * 8);

    // ---- T stage as one K=512 GEMM, 2-buffer pipeline (R4 schedule) ----
    // iter p: VMW4 (plane p landed; plane p+1's 4 loads stay in flight); BAR;
    // compute from WB[p&1]; BAR; stage plane p+2 into WB[p&1].
    f32x4 q00 = {}, q01 = {}, q02 = {}, q03 = {};
    f32x4 q10 = {}, q11 = {}, q12 = {}, q13 = {};
    f32x4 q20 = {}, q21 = {}, q22 = {}, q23 = {};
    f32x4 q30 = {}, q31 = {}, q32 = {}, q33 = {};
#pragma unroll 1
    for (int p = 0; p < 8; ++p) {
        const f16_t* tb = WB[p & 1];
        VMW4(); BAR();
        // per-row-tile q' scales (quad-broadcast ds_read_u16, wave-private)
        f16_t s0 = Qs16[RB + l15][p];
        f16_t s1 = Qs16[RB + 16 + l15][p];
        f16_t s2 = Qs16[RB + 32 + l15][p];
        f16_t s3 = Qs16[RB + 48 + l15][p];
        f16x8 w0 = {s0, s0, s0, s0, s0, s0, s0, s0};
        f16x8 w1 = {s1, s1, s1, s1, s1, s1, s1, s1};
        f16x8 w2 = {s2, s2, s2, s2, s2, s2, s2, s2};
        f16x8 w3 = {s3, s3, s3, s3, s3, s3, s3, s3};
        f16x8 sa00 = ah00 * w0, sa01 = ah01 * w0;
        f16x8 sa10 = ah10 * w1, sa11 = ah11 * w1;
        f16x8 sa20 = ah20 * w2, sa21 = ah21 * w2;
        f16x8 sa30 = ah30 * w3, sa31 = ah31 * w3;
        { B2 B = loadB_lds(tb, 0, l15, quad);
          q00 = mfma1(sa01, B.b1, mfma1(sa00, B.b0, q00));
          q10 = mfma1(sa11, B.b1, mfma1(sa10, B.b0, q10));
          q20 = mfma1(sa21, B.b1, mfma1(sa20, B.b0, q20));
          q30 = mfma1(sa31, B.b1, mfma1(sa30, B.b0, q30)); }
        { B2 B = loadB_lds(tb, 1, l15, quad);
          q01 = mfma1(sa01, B.b1, mfma1(sa00, B.b0, q01));
          q11 = mfma1(sa11, B.b1, mfma1(sa10, B.b0, q11));
          q21 = mfma1(sa21, B.b1, mfma1(sa20, B.b0, q21));
          q31 = mfma1(sa31, B.b1, mfma1(sa30, B.b0, q31)); }
        { B2 B = loadB_lds(tb, 2, l15, quad);
          q02 = mfma1(sa01, B.b1, mfma1(sa00, B.b0, q02));
          q12 = mfma1(sa11, B.b1, mfma1(sa10, B.b0, q12));
          q22 = mfma1(sa21, B.b1, mfma1(sa20, B.b0, q22));
          q32 = mfma1(sa31, B.b1, mfma1(sa30, B.b0, q32)); }
        { B2 B = loadB_lds(tb, 3, l15, quad);
          q03 = mfma1(sa01, B.b1, mfma1(sa00, B.b0, q03));
          q13 = mfma1(sa11, B.b1, mfma1(sa10, B.b0, q13));
          q23 = mfma1(sa21, B.b1, mfma1(sa20, B.b0, q23));
          q33 = mfma1(sa31, B.b1, mfma1(sa30, B.b0, q33)); }
        BAR();
        const f16_t* nsrc = (p < 6) ? (wsf + OFF_T + (p + 2) * 4096)
                                    : ((p == 6) ? (wsf + OFF_KEY) : (wsf + OFF_VAL));
        stage8k(nsrc, WB[p & 1], tid);
    }
    VMW0(); BAR();   // KEY in WB[0], VAL in WB[1] ready

    // ---- fronts: 4 independent row-tiles (k|v + softmax + att + relay) ----
    front_rt(Rf, WB[0], WB[1], l15, quad, 0,  ah00, ah01, q00, q01, q02, q03, kbv, vbv, sc);
    front_rt(Rf, WB[0], WB[1], l15, quad, 16, ah10, ah11, q10, q11, q12, q13, kbv, vbv, sc);
    front_rt(Rf, WB[0], WB[1], l15, quad, 32, ah20, ah21, q20, q21, q22, q23, kbv, vbv, sc);
    front_rt(Rf, WB[0], WB[1], l15, quad, 48, ah30, ah31, q30, q31, q32, q33, kbv, vbv, sc);
    BAR();           // all waves done reading key/val panels
    stage8k(wsf + OFF_D1, WB[0], tid);                 // d1 -> WB[0] (8KB)
    stage4k_r128(wsf + OFF_D2, WB[1], tid);            // d2 -> WB[1][0:2048] (4KB)
    stage4k_r64 (wsf + OFF_D3, WB[1] + 2048, tid);     // d3 -> WB[1][2048:] (4KB, 64B rows)
    VMW0(); BAR();

    // ---- d-chain: two 32-row passes per layer (wave-private, no barriers) ----
    d1_rt(Rf, WB[0], l15, quad, 0,  b1v);
    d1_rt(Rf, WB[0], l15, quad, 32, b1v);
    d2_rt(Rf, WB[1], l15, quad, 0,  b20, b21);
    d2_rt(Rf, WB[1], l15, quad, 32, b20, b21);

    float* __restrict__ obase = out + (t0 + RB) * 64;
    const char* d3b = (const char*)(&WB[1][2048]);
    d3_rt(Rf, Of, d3b, l15, quad, lane, 0,  b3v, obase);
    d3_rt(Rf, Of, d3b, l15, quad, lane, 32, b3v, obase);
}

extern "C" void kernel_launch(void* const* d_in, const int* in_sizes, int n_in,
                              void* d_out, int out_size, void* d_ws, size_t ws_size,
                              hipStream_t stream) {
    (void)in_sizes; (void)n_in; (void)out_size; (void)ws_size;
    const float* kv_in = (const float*)d_in[0];
    const float* q_in  = (const float*)d_in[1];
    const float* keyW  = (const float*)d_in[2];
    const float* keyB  = (const float*)d_in[3];
    const float* valW  = (const float*)d_in[4];
    const float* valB  = (const float*)d_in[5];
    const float* TW    = (const float*)d_in[6];
    const float* TB    = (const float*)d_in[7];
    const float* d1W   = (const float*)d_in[8];
    const float* d1B   = (const float*)d_in[9];
    const float* d2W   = (const float*)d_in[10];
    const float* d2B   = (const float*)d_in[11];
    const float* d3W   = (const float*)d_in[12];
    const float* d3B   = (const float*)d_in[13];
    const float* scale = (const float*)d_in[14];
    f16_t* wsf = (f16_t*)d_ws;
    float* outp = (float*)d_out;

    prep_w<<<(WTOT + 255) / 256, 256, 0, stream>>>(keyW, valW, TW, TB, d1W, d2W, d3W, wsf);
    fused_mfma<<<NTOK / MT, TPB, 0, stream>>>(kv_in, q_in, keyB, valB,
                                              d1B, d2B, d3B, scale, wsf, outp);
}